// Round 1
// baseline (1106.659 us; speedup 1.0000x reference)
//
#include <hip/hip_runtime.h>

typedef __attribute__((ext_vector_type(4))) float f32x4;
typedef __attribute__((ext_vector_type(8))) short short8;
typedef __attribute__((ext_vector_type(2))) unsigned int uint2v;

#define MFMA_BF16(a,b,c) __builtin_amdgcn_mfma_f32_16x16x32_bf16(a,b,c,0,0,0)

__device__ __forceinline__ unsigned short bf16_of(float f) {
  union { float f; unsigned int u; } v; v.f = f;
  unsigned int r = v.u + 0x7fffu + ((v.u >> 16) & 1u);
  return (unsigned short)(r >> 16);
}

__device__ __forceinline__ void gload_lds16(const void* g, void* l) {
  __builtin_amdgcn_global_load_lds(
      (const __attribute__((address_space(1))) unsigned int*)g,
      (__attribute__((address_space(3))) unsigned int*)l, 16, 0, 0);
}

// ---------------------------------------------------------------------------
// K1: weight transpose + cast. Wt[n][k] = bf16(W[k][n]) for 4 E x E matrices.
// ---------------------------------------------------------------------------
__global__ __launch_bounds__(256)
void wcast_kernel(const float* __restrict__ W0, const float* __restrict__ W1,
                  const float* __restrict__ W2, const float* __restrict__ W3,
                  unsigned short* __restrict__ wt) {
  __shared__ float tile[64][65];
  const float* W = (blockIdx.z == 0) ? W0 : (blockIdx.z == 1) ? W1
                 : (blockIdx.z == 2) ? W2 : W3;
  unsigned short* Wt = wt + (size_t)blockIdx.z * (1024u * 1024u);
  int k0 = blockIdx.x * 64, n0 = blockIdx.y * 64;
  int t = threadIdx.x, r = t >> 6, c = t & 63;
#pragma unroll
  for (int i = 0; i < 16; ++i)
    tile[r + i * 4][c] = W[(size_t)(k0 + r + i * 4) * 1024 + n0 + c];
  __syncthreads();
#pragma unroll
  for (int i = 0; i < 16; ++i)
    Wt[(size_t)(n0 + r + i * 4) * 1024 + k0 + c] = bf16_of(tile[c][r + i * 4]);
}

// ---------------------------------------------------------------------------
// K2: GEMM  C[65536 x 1024] = A[65536 x 1024] * Bt[1024 x 1024]^T  (+bias)
// MODE 0: A=f32, epilogue relu, store bf16 [B,H,S,D]   (Q and K projections)
// MODE 1: A=f32, no relu,      store bf16 [B,H,D,S]    (V projection, transposed)
// MODE 2: A=bf16 (glds), +bias, store f32 [M,N]        (output projection)
// 128x128 tile, BK=32, 4 waves (2x2) of 64x64, 16x16x32 bf16 MFMA.
// LDS tile layout: row-major [128][32] bf16 with 16B-seg XOR swizzle:
//   byte(r, seg) = r*64 + ((seg ^ (r&3)) << 4)
// ---------------------------------------------------------------------------
template <int MODE>
__global__ __launch_bounds__(256, 2)
void gemm_kernel(const void* __restrict__ A_, const unsigned short* __restrict__ Bt,
                 const float* __restrict__ bias, void* __restrict__ C_) {
  constexpr bool AF32 = (MODE != 2);
  __shared__ unsigned short ldsA[128 * 32];
  __shared__ unsigned short ldsB[128 * 32];

  int bid = blockIdx.x;
  // XCD swizzle: XCD x (= bid&7) gets a contiguous run of m-tiles; the 8
  // n-tiles of one m-tile are adjacent so the A-panel stays in that XCD's L2.
  int mt = (bid & 7) * 64 + (bid >> 6);
  int nt = (bid >> 3) & 7;
  int m0 = mt * 128, n0 = nt * 128;

  int tid = threadIdx.x;
  int w = tid >> 6, l = tid & 63;
  int wm = w >> 1, wn = w & 1;
  int li = l & 15, grp = l >> 4;

  f32x4 acc[4][4] = {};

  const float* Af = (const float*)A_;
  const unsigned short* Ab = (const unsigned short*)A_;

  // f32-A staging map: thread t covers rows (t>>3)+32i, 16B-chunk c4=t&7
  int ar = tid >> 3;   // 0..31
  int ac4 = tid & 7;   // 0..7
  // glds staging map: chunk c covers 16 rows; lane l -> row c*16+(l>>2),
  // physical seg l&3; pre-swizzle global seg so linear LDS dest = swizzled.
  int rA = l >> 2;
  int pseg = l & 3;

  f32x4 areg[4];
  if constexpr (AF32) {
#pragma unroll
    for (int i = 0; i < 4; ++i)
      areg[i] = *(const f32x4*)(Af + (size_t)(m0 + ar + 32 * i) * 1024 + ac4 * 4);
  }

  for (int kt = 0; kt < 32; ++kt) {
    int k0 = kt * 32;
    // ---- stage A ----
    if constexpr (AF32) {
#pragma unroll
      for (int i = 0; i < 4; ++i) {
        int row = ar + 32 * i;
        uint2v pk;
        pk.x = (unsigned int)bf16_of(areg[i][0]) | ((unsigned int)bf16_of(areg[i][1]) << 16);
        pk.y = (unsigned int)bf16_of(areg[i][2]) | ((unsigned int)bf16_of(areg[i][3]) << 16);
        int seg = ac4 >> 1, sub = ac4 & 1;
        int off = row * 64 + ((seg ^ (row & 3)) << 4) + sub * 8;
        *(uint2v*)((char*)ldsA + off) = pk;
      }
    } else {
#pragma unroll
      for (int i = 0; i < 2; ++i) {
        int c = w * 2 + i;
        int row = c * 16 + rA;
        int s = pseg ^ (row & 3);
        gload_lds16(Ab + (size_t)(m0 + row) * 1024 + k0 + s * 8,
                    (char*)ldsA + c * 1024);
      }
    }
    // ---- stage B ----
#pragma unroll
    for (int i = 0; i < 2; ++i) {
      int c = w * 2 + i;
      int row = c * 16 + rA;
      int s = pseg ^ (row & 3);
      gload_lds16(Bt + (size_t)(n0 + row) * 1024 + k0 + s * 8,
                  (char*)ldsB + c * 1024);
    }
    // ---- prefetch next A (f32 path) ----
    if constexpr (AF32) {
      if (kt < 31) {
#pragma unroll
        for (int i = 0; i < 4; ++i)
          areg[i] = *(const f32x4*)(Af + (size_t)(m0 + ar + 32 * i) * 1024 + (k0 + 32) + ac4 * 4);
      }
    }
    __syncthreads();
    // ---- compute ----
    short8 af[4], bf[4];
#pragma unroll
    for (int mi = 0; mi < 4; ++mi) {
      int row = wm * 64 + mi * 16 + li;
      af[mi] = *(const short8*)((const char*)ldsA + row * 64 + ((grp ^ (row & 3)) << 4));
    }
#pragma unroll
    for (int ni = 0; ni < 4; ++ni) {
      int row = wn * 64 + ni * 16 + li;
      bf[ni] = *(const short8*)((const char*)ldsB + row * 64 + ((grp ^ (row & 3)) << 4));
    }
#pragma unroll
    for (int mi = 0; mi < 4; ++mi)
#pragma unroll
      for (int ni = 0; ni < 4; ++ni)
        acc[mi][ni] = MFMA_BF16(af[mi], bf[ni], acc[mi][ni]);
    __syncthreads();
  }

  // ---- epilogue ----
  int mrow0 = m0 + wm * 64;   // 64-aligned -> single batch b per wave
  int ncol0 = n0 + wn * 64;   // 64-aligned -> single head h per wave
  float bvv[4];
#pragma unroll
  for (int ni = 0; ni < 4; ++ni) bvv[ni] = bias[ncol0 + ni * 16 + li];

  if constexpr (MODE == 2) {
    float* C = (float*)C_;
#pragma unroll
    for (int mi = 0; mi < 4; ++mi)
#pragma unroll
      for (int ni = 0; ni < 4; ++ni)
#pragma unroll
        for (int j = 0; j < 4; ++j)
          C[(size_t)(mrow0 + mi * 16 + grp * 4 + j) * 1024 + ncol0 + ni * 16 + li] =
              acc[mi][ni][j] + bvv[ni];
  } else if constexpr (MODE == 0) {
    unsigned short* C = (unsigned short*)C_;
    int b = mrow0 >> 6, h = ncol0 >> 6;
    unsigned short* base = C + (size_t)b * 65536 + (size_t)h * 4096;  // [b][h][s][d]
#pragma unroll
    for (int mi = 0; mi < 4; ++mi)
#pragma unroll
      for (int ni = 0; ni < 4; ++ni)
#pragma unroll
        for (int j = 0; j < 4; ++j) {
          float v = acc[mi][ni][j] + bvv[ni];
          v = fmaxf(v, 0.0f);  // ReLU on Q/K
          base[(mi * 16 + grp * 4 + j) * 64 + ni * 16 + li] = bf16_of(v);
        }
  } else {  // MODE 1: V, transposed store [b][h][d][s]
    unsigned short* C = (unsigned short*)C_;
    int b = mrow0 >> 6, h = ncol0 >> 6;
    unsigned short* base = C + (size_t)b * 65536 + (size_t)h * 4096;
#pragma unroll
    for (int mi = 0; mi < 4; ++mi)
#pragma unroll
      for (int ni = 0; ni < 4; ++ni) {
        float v0 = acc[mi][ni][0] + bvv[ni];
        float v1 = acc[mi][ni][1] + bvv[ni];
        float v2 = acc[mi][ni][2] + bvv[ni];
        float v3 = acc[mi][ni][3] + bvv[ni];
        uint2v pk;
        pk.x = (unsigned int)bf16_of(v0) | ((unsigned int)bf16_of(v1) << 16);
        pk.y = (unsigned int)bf16_of(v2) | ((unsigned int)bf16_of(v3) << 16);
        // d = ni*16+li (row of Vt), s = mi*16 + grp*4 .. +3 (4 consecutive)
        *(uint2v*)(base + (ni * 16 + li) * 64 + mi * 16 + grp * 4) = pk;
      }
  }
}

// ---------------------------------------------------------------------------
// K3: attention. One wave per (b,h). Q,K: [b][h][s][d] bf16 (ReLU'd, biased),
// V: [b][h][d][s] bf16. Out: [b][s][h][d] bf16.
// S = (Q K^T) * 0.125, causal mask, softmax rows, O = P V.
// ---------------------------------------------------------------------------
__global__ __launch_bounds__(64)
void attn_kernel(const unsigned short* __restrict__ qw,
                 const unsigned short* __restrict__ kw,
                 const unsigned short* __restrict__ vw,
                 unsigned short* __restrict__ aw) {
  __shared__ unsigned short p_lds[64 * 72];  // stride 72 breaks bank conflicts
  int bh = blockIdx.x;
  int b = bh >> 4, h = bh & 15;
  int l = threadIdx.x;
  int li = l & 15, grp = l >> 4;
  const unsigned short* qb = qw + (size_t)bh * 4096;
  const unsigned short* kb = kw + (size_t)bh * 4096;
  const unsigned short* vb = vw + (size_t)bh * 4096;

  short8 aq[4][2], bk_[4][2];
#pragma unroll
  for (int mi = 0; mi < 4; ++mi)
#pragma unroll
    for (int ks = 0; ks < 2; ++ks) {
      aq[mi][ks]  = *(const short8*)(qb + (mi * 16 + li) * 64 + ks * 32 + grp * 8);
      bk_[mi][ks] = *(const short8*)(kb + (mi * 16 + li) * 64 + ks * 32 + grp * 8);
    }

  f32x4 sf[4][4];
#pragma unroll
  for (int mi = 0; mi < 4; ++mi)
#pragma unroll
    for (int ni = 0; ni < 4; ++ni) {
      f32x4 t = {};
      t = MFMA_BF16(aq[mi][0], bk_[ni][0], t);
      t = MFMA_BF16(aq[mi][1], bk_[ni][1], t);
      sf[mi][ni] = t;
    }

  // scale + causal mask + row softmax (row lives in 16 lanes w/ same grp)
#pragma unroll
  for (int mi = 0; mi < 4; ++mi) {
#pragma unroll
    for (int j = 0; j < 4; ++j) {
      int row = mi * 16 + grp * 4 + j;
      float mx = -1e30f;
#pragma unroll
      for (int ni = 0; ni < 4; ++ni) {
        int col = ni * 16 + li;
        float v = sf[mi][ni][j] * 0.125f;
        v = (col <= row) ? v : -1e30f;
        sf[mi][ni][j] = v;
        mx = fmaxf(mx, v);
      }
#pragma unroll
      for (int sh = 1; sh < 16; sh <<= 1) mx = fmaxf(mx, __shfl_xor(mx, sh, 64));
      float sum = 0.0f;
#pragma unroll
      for (int ni = 0; ni < 4; ++ni) {
        float e = __expf(sf[mi][ni][j] - mx);
        sf[mi][ni][j] = e;
        sum += e;
      }
#pragma unroll
      for (int sh = 1; sh < 16; sh <<= 1) sum += __shfl_xor(sum, sh, 64);
      float rr = 1.0f / sum;
#pragma unroll
      for (int ni = 0; ni < 4; ++ni) sf[mi][ni][j] *= rr;
    }
  }

  // P (C-layout) -> LDS so PV can read A-layout fragments
#pragma unroll
  for (int mi = 0; mi < 4; ++mi)
#pragma unroll
    for (int ni = 0; ni < 4; ++ni)
#pragma unroll
      for (int j = 0; j < 4; ++j)
        p_lds[(mi * 16 + grp * 4 + j) * 72 + ni * 16 + li] = bf16_of(sf[mi][ni][j]);
  __syncthreads();

  short8 pa[4][2], bv_[4][2];
#pragma unroll
  for (int mi = 0; mi < 4; ++mi)
#pragma unroll
    for (int ks = 0; ks < 2; ++ks)
      pa[mi][ks] = *(const short8*)(p_lds + (mi * 16 + li) * 72 + ks * 32 + grp * 8);
#pragma unroll
  for (int ni = 0; ni < 4; ++ni)
#pragma unroll
    for (int ks = 0; ks < 2; ++ks)
      bv_[ni][ks] = *(const short8*)(vb + (ni * 16 + li) * 64 + ks * 32 + grp * 8);

  f32x4 of[4][4];
#pragma unroll
  for (int mi = 0; mi < 4; ++mi)
#pragma unroll
    for (int ni = 0; ni < 4; ++ni) {
      f32x4 t = {};
      t = MFMA_BF16(pa[mi][0], bv_[ni][0], t);
      t = MFMA_BF16(pa[mi][1], bv_[ni][1], t);
      of[mi][ni] = t;
    }

  // store [b][s][h][d]
  unsigned short* ab = aw + (size_t)b * 65536 + (size_t)h * 64;
#pragma unroll
  for (int mi = 0; mi < 4; ++mi)
#pragma unroll
    for (int ni = 0; ni < 4; ++ni)
#pragma unroll
      for (int j = 0; j < 4; ++j)
        ab[(size_t)(mi * 16 + grp * 4 + j) * 1024 + ni * 16 + li] = bf16_of(of[mi][ni][j]);
}

// ---------------------------------------------------------------------------
extern "C" void kernel_launch(void* const* d_in, const int* in_sizes, int n_in,
                              void* d_out, int out_size, void* d_ws, size_t ws_size,
                              hipStream_t stream) {
  (void)in_sizes; (void)n_in; (void)out_size; (void)ws_size;
  const float* query = (const float*)d_in[0];
  const float* key   = (const float*)d_in[1];
  const float* value = (const float*)d_in[2];
  const float* Wq = (const float*)d_in[3];
  const float* bq = (const float*)d_in[4];
  const float* Wk = (const float*)d_in[5];
  const float* bk = (const float*)d_in[6];
  const float* Wv = (const float*)d_in[7];
  const float* bv = (const float*)d_in[8];
  const float* Wo = (const float*)d_in[9];
  const float* bo = (const float*)d_in[10];
  float* out = (float*)d_out;

  // workspace layout (545 MB):
  //   [0,8MB)        4x bf16 W^T (each 1024x1024)
  //   then 4x 128MB  q_ws [B,H,S,D], k_ws [B,H,S,D], v_ws [B,H,D,S], attn [B,S,H,D]
  unsigned short* wt = (unsigned short*)d_ws;
  const size_t NE = (size_t)67108864;  // B*S*E
  unsigned short* qw = wt + (size_t)4 * 1024 * 1024;
  unsigned short* kw = qw + NE;
  unsigned short* vw = kw + NE;
  unsigned short* aw = vw + NE;

  wcast_kernel<<<dim3(16, 16, 4), 256, 0, stream>>>(Wq, Wk, Wv, Wo, wt);
  gemm_kernel<0><<<dim3(4096), 256, 0, stream>>>(query, wt + (size_t)0 * 1048576, bq, qw);
  gemm_kernel<0><<<dim3(4096), 256, 0, stream>>>(key,   wt + (size_t)1 * 1048576, bk, kw);
  gemm_kernel<1><<<dim3(4096), 256, 0, stream>>>(value, wt + (size_t)2 * 1048576, bv, vw);
  attn_kernel<<<dim3(16384), 64, 0, stream>>>(qw, kw, vw, aw);
  gemm_kernel<2><<<dim3(4096), 256, 0, stream>>>(aw, wt + (size_t)3 * 1048576, bo, out);
}

// Round 2
// 1003.339 us; speedup vs baseline: 1.1030x; 1.1030x over previous
//
#include <hip/hip_runtime.h>

typedef __attribute__((ext_vector_type(4))) float f32x4;
typedef __attribute__((ext_vector_type(8))) short short8;
typedef __attribute__((ext_vector_type(2))) unsigned int uint2v;

#define MFMA_BF16(a,b,c) __builtin_amdgcn_mfma_f32_16x16x32_bf16(a,b,c,0,0,0)

__device__ __forceinline__ unsigned short bf16_of(float f) {
  union { float f; unsigned int u; } v; v.f = f;
  unsigned int r = v.u + 0x7fffu + ((v.u >> 16) & 1u);
  return (unsigned short)(r >> 16);
}

// HW packed f32->bf16 (RNE): dst[15:0]=bf16(lo), dst[31:16]=bf16(hi)
__device__ __forceinline__ unsigned int cvt_pk_bf16(float lo, float hi) {
  unsigned int r;
  asm("v_cvt_pk_bf16_f32 %0, %1, %2" : "=v"(r) : "v"(lo), "v"(hi));
  return r;
}

// bank-spreading seg swizzle: quad index (4r + swz(r)) mod 8 covers all 8
// bank-quads exactly twice over any 16 consecutive rows -> 2-way (free).
__device__ __forceinline__ int swz(int r) { return (r + (r >> 2)) & 3; }

__device__ __forceinline__ void gload_lds16(const void* g, void* l) {
  __builtin_amdgcn_global_load_lds(
      (const __attribute__((address_space(1))) unsigned int*)g,
      (__attribute__((address_space(3))) unsigned int*)l, 16, 0, 0);
}

// ---------------------------------------------------------------------------
// K1: weight transpose + cast. Wt[n][k] = bf16(W[k][n]) for 4 E x E matrices.
// ---------------------------------------------------------------------------
__global__ __launch_bounds__(256)
void wcast_kernel(const float* __restrict__ W0, const float* __restrict__ W1,
                  const float* __restrict__ W2, const float* __restrict__ W3,
                  unsigned short* __restrict__ wt) {
  __shared__ float tile[64][65];
  const float* W = (blockIdx.z == 0) ? W0 : (blockIdx.z == 1) ? W1
                 : (blockIdx.z == 2) ? W2 : W3;
  unsigned short* Wt = wt + (size_t)blockIdx.z * (1024u * 1024u);
  int k0 = blockIdx.x * 64, n0 = blockIdx.y * 64;
  int t = threadIdx.x, r = t >> 6, c = t & 63;
#pragma unroll
  for (int i = 0; i < 16; ++i)
    tile[r + i * 4][c] = W[(size_t)(k0 + r + i * 4) * 1024 + n0 + c];
  __syncthreads();
#pragma unroll
  for (int i = 0; i < 16; ++i)
    Wt[(size_t)(n0 + r + i * 4) * 1024 + k0 + c] = bf16_of(tile[c][r + i * 4]);
}

// ---------------------------------------------------------------------------
// K2: GEMM  C[65536 x 1024] = A[65536 x 1024] * Bt[1024 x 1024]^T  (+bias)
// MODE 0: A=f32, epilogue relu, store bf16 [B,H,S,D]   (Q and K projections)
// MODE 1: A=f32, no relu,      store bf16 [B,H,D,S]    (V projection, transposed)
// MODE 2: A=bf16 (glds), +bias, store f32 [M,N]        (output projection)
// 128x128 tile, BK=32, 4 waves (2x2) of 64x64, 16x16x32 bf16 MFMA.
// LDS tile: row-major [128][32] bf16; 16B-seg phys slot p = seg ^ swz(row).
// ---------------------------------------------------------------------------
template <int MODE>
__global__ __launch_bounds__(256, 4)
void gemm_kernel(const void* __restrict__ A_, const unsigned short* __restrict__ Bt,
                 const float* __restrict__ bias, void* __restrict__ C_) {
  constexpr bool AF32 = (MODE != 2);
  __shared__ unsigned short ldsA[128 * 32];
  __shared__ unsigned short ldsB[128 * 32];

  int bid = blockIdx.x;
  // XCD swizzle: XCD x (= bid&7) gets a contiguous run of m-tiles; the 8
  // n-tiles of one m-tile are adjacent so the A-panel stays in that XCD's L2.
  int mt = (bid & 7) * 64 + (bid >> 6);
  int nt = (bid >> 3) & 7;
  int m0 = mt * 128, n0 = nt * 128;

  int tid = threadIdx.x;
  int w = tid >> 6, l = tid & 63;
  int wm = w >> 1, wn = w & 1;
  int li = l & 15, grp = l >> 4;

  f32x4 acc[4][4] = {};

  const float* Af = (const float*)A_;
  const unsigned short* Ab = (const unsigned short*)A_;

  // f32-A staging map: thread t covers rows (t>>3)+32i, 16B(f32x4) chunk ac4
  int ar = tid >> 3;   // 0..31
  int ac4 = tid & 7;   // 0..7
  // glds staging map: chunk c covers 16 rows; lane l -> row c*16+(l>>2),
  // physical slot l&3; pre-swizzle global seg so linear LDS dest = swizzled.
  int rA = l >> 2;
  int pseg = l & 3;

  f32x4 areg[4];
  if constexpr (AF32) {
#pragma unroll
    for (int i = 0; i < 4; ++i)
      areg[i] = *(const f32x4*)(Af + (size_t)(m0 + ar + 32 * i) * 1024 + ac4 * 4);
  }

  for (int kt = 0; kt < 32; ++kt) {
    int k0 = kt * 32;
    // ---- stage A ----
    if constexpr (AF32) {
#pragma unroll
      for (int i = 0; i < 4; ++i) {
        int row = ar + 32 * i;
        uint2v pk;
        pk.x = cvt_pk_bf16(areg[i][0], areg[i][1]);
        pk.y = cvt_pk_bf16(areg[i][2], areg[i][3]);
        int seg = ac4 >> 1, sub = ac4 & 1;
        int off = row * 64 + ((seg ^ swz(row)) << 4) + sub * 8;
        *(uint2v*)((char*)ldsA + off) = pk;
      }
    } else {
#pragma unroll
      for (int i = 0; i < 2; ++i) {
        int c = w * 2 + i;
        int row = c * 16 + rA;
        int s = pseg ^ swz(row);
        gload_lds16(Ab + (size_t)(m0 + row) * 1024 + k0 + s * 8,
                    (char*)ldsA + c * 1024);
      }
    }
    // ---- stage B ----
#pragma unroll
    for (int i = 0; i < 2; ++i) {
      int c = w * 2 + i;
      int row = c * 16 + rA;
      int s = pseg ^ swz(row);
      gload_lds16(Bt + (size_t)(n0 + row) * 1024 + k0 + s * 8,
                  (char*)ldsB + c * 1024);
    }
    // ---- prefetch next A (f32 path) ----
    if constexpr (AF32) {
      if (kt < 31) {
#pragma unroll
        for (int i = 0; i < 4; ++i)
          areg[i] = *(const f32x4*)(Af + (size_t)(m0 + ar + 32 * i) * 1024 + (k0 + 32) + ac4 * 4);
      }
    }
    __syncthreads();
    // ---- compute ----
    short8 af[4], bf[4];
#pragma unroll
    for (int mi = 0; mi < 4; ++mi) {
      int row = wm * 64 + mi * 16 + li;
      af[mi] = *(const short8*)((const char*)ldsA + row * 64 + ((grp ^ swz(row)) << 4));
    }
#pragma unroll
    for (int ni = 0; ni < 4; ++ni) {
      int row = wn * 64 + ni * 16 + li;
      bf[ni] = *(const short8*)((const char*)ldsB + row * 64 + ((grp ^ swz(row)) << 4));
    }
#pragma unroll
    for (int mi = 0; mi < 4; ++mi)
#pragma unroll
      for (int ni = 0; ni < 4; ++ni)
        acc[mi][ni] = MFMA_BF16(af[mi], bf[ni], acc[mi][ni]);
    __syncthreads();
  }

  // ---- epilogue ----
  int mrow0 = m0 + wm * 64;   // 64-aligned -> single batch b per wave
  int ncol0 = n0 + wn * 64;   // 64-aligned -> single head h per wave
  float bvv[4];
#pragma unroll
  for (int ni = 0; ni < 4; ++ni) bvv[ni] = bias[ncol0 + ni * 16 + li];

  if constexpr (MODE == 2) {
    float* C = (float*)C_;
#pragma unroll
    for (int mi = 0; mi < 4; ++mi)
#pragma unroll
      for (int ni = 0; ni < 4; ++ni)
#pragma unroll
        for (int j = 0; j < 4; ++j)
          C[(size_t)(mrow0 + mi * 16 + grp * 4 + j) * 1024 + ncol0 + ni * 16 + li] =
              acc[mi][ni][j] + bvv[ni];
  } else if constexpr (MODE == 0) {
    unsigned short* C = (unsigned short*)C_;
    int b = mrow0 >> 6, h = ncol0 >> 6;
    unsigned short* base = C + (size_t)b * 65536 + (size_t)h * 4096;  // [b][h][s][d]
#pragma unroll
    for (int mi = 0; mi < 4; ++mi)
#pragma unroll
      for (int ni = 0; ni < 4; ++ni)
#pragma unroll
        for (int j = 0; j < 4; ++j) {
          float v = acc[mi][ni][j] + bvv[ni];
          v = fmaxf(v, 0.0f);  // ReLU on Q/K
          base[(mi * 16 + grp * 4 + j) * 64 + ni * 16 + li] = bf16_of(v);
        }
  } else {  // MODE 1: V, transposed store [b][h][d][s]
    unsigned short* C = (unsigned short*)C_;
    int b = mrow0 >> 6, h = ncol0 >> 6;
    unsigned short* base = C + (size_t)b * 65536 + (size_t)h * 4096;
#pragma unroll
    for (int mi = 0; mi < 4; ++mi)
#pragma unroll
      for (int ni = 0; ni < 4; ++ni) {
        uint2v pk;
        pk.x = cvt_pk_bf16(acc[mi][ni][0] + bvv[ni], acc[mi][ni][1] + bvv[ni]);
        pk.y = cvt_pk_bf16(acc[mi][ni][2] + bvv[ni], acc[mi][ni][3] + bvv[ni]);
        // d = ni*16+li (row of Vt), s = mi*16 + grp*4 .. +3 (4 consecutive)
        *(uint2v*)(base + (ni * 16 + li) * 64 + mi * 16 + grp * 4) = pk;
      }
  }
}

// ---------------------------------------------------------------------------
// K3: attention. One wave per (b,h). Q,K: [b][h][s][d] bf16 (ReLU'd, biased),
// V: [b][h][d][s] bf16. Out: [b][s][h][d] bf16.
// S = (Q K^T) * 0.125, causal mask, softmax rows, O = P V.
// ---------------------------------------------------------------------------
__global__ __launch_bounds__(64)
void attn_kernel(const unsigned short* __restrict__ qw,
                 const unsigned short* __restrict__ kw,
                 const unsigned short* __restrict__ vw,
                 unsigned short* __restrict__ aw) {
  __shared__ unsigned short p_lds[64 * 72];  // stride 72 breaks bank conflicts
  int bh = blockIdx.x;
  int b = bh >> 4, h = bh & 15;
  int l = threadIdx.x;
  int li = l & 15, grp = l >> 4;
  const unsigned short* qb = qw + (size_t)bh * 4096;
  const unsigned short* kb = kw + (size_t)bh * 4096;
  const unsigned short* vb = vw + (size_t)bh * 4096;

  short8 aq[4][2], bk_[4][2];
#pragma unroll
  for (int mi = 0; mi < 4; ++mi)
#pragma unroll
    for (int ks = 0; ks < 2; ++ks) {
      aq[mi][ks]  = *(const short8*)(qb + (mi * 16 + li) * 64 + ks * 32 + grp * 8);
      bk_[mi][ks] = *(const short8*)(kb + (mi * 16 + li) * 64 + ks * 32 + grp * 8);
    }

  f32x4 sf[4][4];
#pragma unroll
  for (int mi = 0; mi < 4; ++mi)
#pragma unroll
    for (int ni = 0; ni < 4; ++ni) {
      f32x4 t = {};
      t = MFMA_BF16(aq[mi][0], bk_[ni][0], t);
      t = MFMA_BF16(aq[mi][1], bk_[ni][1], t);
      sf[mi][ni] = t;
    }

  // scale + causal mask + row softmax (row lives in 16 lanes w/ same grp)
#pragma unroll
  for (int mi = 0; mi < 4; ++mi) {
#pragma unroll
    for (int j = 0; j < 4; ++j) {
      int row = mi * 16 + grp * 4 + j;
      float mx = -1e30f;
#pragma unroll
      for (int ni = 0; ni < 4; ++ni) {
        int col = ni * 16 + li;
        float v = sf[mi][ni][j] * 0.125f;
        v = (col <= row) ? v : -1e30f;
        sf[mi][ni][j] = v;
        mx = fmaxf(mx, v);
      }
#pragma unroll
      for (int sh = 1; sh < 16; sh <<= 1) mx = fmaxf(mx, __shfl_xor(mx, sh, 64));
      float sum = 0.0f;
#pragma unroll
      for (int ni = 0; ni < 4; ++ni) {
        float e = __expf(sf[mi][ni][j] - mx);
        sf[mi][ni][j] = e;
        sum += e;
      }
#pragma unroll
      for (int sh = 1; sh < 16; sh <<= 1) sum += __shfl_xor(sum, sh, 64);
      float rr = 1.0f / sum;
#pragma unroll
      for (int ni = 0; ni < 4; ++ni) sf[mi][ni][j] *= rr;
    }
  }

  // P (C-layout) -> LDS so PV can read A-layout fragments
#pragma unroll
  for (int mi = 0; mi < 4; ++mi)
#pragma unroll
    for (int ni = 0; ni < 4; ++ni)
#pragma unroll
      for (int j = 0; j < 4; ++j)
        p_lds[(mi * 16 + grp * 4 + j) * 72 + ni * 16 + li] = bf16_of(sf[mi][ni][j]);
  __syncthreads();

  short8 pa[4][2], bv_[4][2];
#pragma unroll
  for (int mi = 0; mi < 4; ++mi)
#pragma unroll
    for (int ks = 0; ks < 2; ++ks)
      pa[mi][ks] = *(const short8*)(p_lds + (mi * 16 + li) * 72 + ks * 32 + grp * 8);
#pragma unroll
  for (int ni = 0; ni < 4; ++ni)
#pragma unroll
    for (int ks = 0; ks < 2; ++ks)
      bv_[ni][ks] = *(const short8*)(vb + (ni * 16 + li) * 64 + ks * 32 + grp * 8);

  f32x4 of[4][4];
#pragma unroll
  for (int mi = 0; mi < 4; ++mi)
#pragma unroll
    for (int ni = 0; ni < 4; ++ni) {
      f32x4 t = {};
      t = MFMA_BF16(pa[mi][0], bv_[ni][0], t);
      t = MFMA_BF16(pa[mi][1], bv_[ni][1], t);
      of[mi][ni] = t;
    }

  // store [b][s][h][d]
  unsigned short* ab = aw + (size_t)b * 65536 + (size_t)h * 64;
#pragma unroll
  for (int mi = 0; mi < 4; ++mi)
#pragma unroll
    for (int ni = 0; ni < 4; ++ni)
#pragma unroll
      for (int j = 0; j < 4; ++j)
        ab[(size_t)(mi * 16 + grp * 4 + j) * 1024 + ni * 16 + li] = bf16_of(of[mi][ni][j]);
}

// ---------------------------------------------------------------------------
extern "C" void kernel_launch(void* const* d_in, const int* in_sizes, int n_in,
                              void* d_out, int out_size, void* d_ws, size_t ws_size,
                              hipStream_t stream) {
  (void)in_sizes; (void)n_in; (void)out_size; (void)ws_size;
  const float* query = (const float*)d_in[0];
  const float* key   = (const float*)d_in[1];
  const float* value = (const float*)d_in[2];
  const float* Wq = (const float*)d_in[3];
  const float* bq = (const float*)d_in[4];
  const float* Wk = (const float*)d_in[5];
  const float* bk = (const float*)d_in[6];
  const float* Wv = (const float*)d_in[7];
  const float* bv = (const float*)d_in[8];
  const float* Wo = (const float*)d_in[9];
  const float* bo = (const float*)d_in[10];
  float* out = (float*)d_out;

  // workspace layout (545 MB):
  //   [0,8MB)        4x bf16 W^T (each 1024x1024)
  //   then 4x 128MB  q_ws [B,H,S,D], k_ws [B,H,S,D], v_ws [B,H,D,S], attn [B,S,H,D]
  unsigned short* wt = (unsigned short*)d_ws;
  const size_t NE = (size_t)67108864;  // B*S*E
  unsigned short* qw = wt + (size_t)4 * 1024 * 1024;
  unsigned short* kw = qw + NE;
  unsigned short* vw = kw + NE;
  unsigned short* aw = vw + NE;

  wcast_kernel<<<dim3(16, 16, 4), 256, 0, stream>>>(Wq, Wk, Wv, Wo, wt);
  gemm_kernel<0><<<dim3(4096), 256, 0, stream>>>(query, wt + (size_t)0 * 1048576, bq, qw);
  gemm_kernel<0><<<dim3(4096), 256, 0, stream>>>(key,   wt + (size_t)1 * 1048576, bk, kw);
  gemm_kernel<1><<<dim3(4096), 256, 0, stream>>>(value, wt + (size_t)2 * 1048576, bv, vw);
  attn_kernel<<<dim3(16384), 64, 0, stream>>>(qw, kw, vw, aw);
  gemm_kernel<2><<<dim3(4096), 256, 0, stream>>>(aw, wt + (size_t)3 * 1048576, bo, out);
}

// Round 4
// 923.314 us; speedup vs baseline: 1.1986x; 1.0867x over previous
//
#include <hip/hip_runtime.h>

typedef __attribute__((ext_vector_type(4))) float f32x4;
typedef __attribute__((ext_vector_type(8))) short short8;
typedef __attribute__((ext_vector_type(2))) unsigned int uint2v;
typedef __attribute__((ext_vector_type(4))) unsigned int uint4v;

#define MFMA_BF16(a,b,c) __builtin_amdgcn_mfma_f32_16x16x32_bf16(a,b,c,0,0,0)

__device__ __forceinline__ unsigned short bf16_of(float f) {
  union { float f; unsigned int u; } v; v.f = f;
  unsigned int r = v.u + 0x7fffu + ((v.u >> 16) & 1u);
  return (unsigned short)(r >> 16);
}

// HW packed f32->bf16 (RNE): dst[15:0]=bf16(lo), dst[31:16]=bf16(hi)
__device__ __forceinline__ unsigned int cvt_pk_bf16(float lo, float hi) {
  unsigned int r;
  asm("v_cvt_pk_bf16_f32 %0, %1, %2" : "=v"(r) : "v"(lo), "v"(hi));
  return r;
}

__device__ __forceinline__ void gload_lds16(const void* g, void* l) {
  __builtin_amdgcn_global_load_lds(
      (const __attribute__((address_space(1))) unsigned int*)g,
      (__attribute__((address_space(3))) unsigned int*)l, 16, 0, 0);
}

// ---------------------------------------------------------------------------
// K1: weight transpose + cast. Wt[n][k] = bf16(W[k][n]) for 4 E x E matrices.
// ---------------------------------------------------------------------------
__global__ __launch_bounds__(256)
void wcast_kernel(const float* __restrict__ W0, const float* __restrict__ W1,
                  const float* __restrict__ W2, const float* __restrict__ W3,
                  unsigned short* __restrict__ wt) {
  __shared__ float tile[64][65];
  const float* W = (blockIdx.z == 0) ? W0 : (blockIdx.z == 1) ? W1
                 : (blockIdx.z == 2) ? W2 : W3;
  unsigned short* Wt = wt + (size_t)blockIdx.z * (1024u * 1024u);
  int k0 = blockIdx.x * 64, n0 = blockIdx.y * 64;
  int t = threadIdx.x, r = t >> 6, c = t & 63;
#pragma unroll
  for (int i = 0; i < 16; ++i)
    tile[r + i * 4][c] = W[(size_t)(k0 + r + i * 4) * 1024 + n0 + c];
  __syncthreads();
#pragma unroll
  for (int i = 0; i < 16; ++i)
    Wt[(size_t)(n0 + r + i * 4) * 1024 + k0 + c] = bf16_of(tile[c][r + i * 4]);
}

// ---------------------------------------------------------------------------
// K2: GEMM  C[65536 x 1024] = A[65536 x 1024] * Bt[1024 x 1024]^T  (+bias)
// MODE 0: A=f32, relu, store bf16 [B,H,S,D];  MODE 1: A=f32, store bf16 [B,H,D,S]
// MODE 2: A=bf16 (glds), +bias, store f32 [M,N]
// Verified r2 schedule (stage -> sync -> compute -> sync), new parameters:
// BM=128, BN=256, BK=64, 8 waves (2Mx4N) x 64x64 output, 512 threads.
// LDS rows are 128B (full bank wrap): phys 16B slot = slot ^ (row&7) on both
// write and read; glds uses linear dest + the same involution on the source.
// ---------------------------------------------------------------------------
template <int MODE>
__global__ __launch_bounds__(512, 4)
void gemm_kernel(const void* __restrict__ A_, const unsigned short* __restrict__ Bt,
                 const float* __restrict__ bias, void* __restrict__ C_) {
  constexpr bool AF32 = (MODE != 2);
  __shared__ unsigned short ldsA[128 * 64];  // 16KB
  __shared__ unsigned short ldsB[256 * 64];  // 32KB

  int bid = blockIdx.x;
  // XCD swizzle (2048 blocks = 8 XCDs x 256): XCD x gets a contiguous run of
  // 64 m-tiles; the 4 n-tiles of one m-tile are adjacent on that XCD.
  int mt = (bid & 7) * 64 + (bid >> 5);
  int nt = (bid >> 3) & 3;
  int m0 = mt * 128, n0 = nt * 256;

  int tid = threadIdx.x;
  int w = tid >> 6, l = tid & 63;
  int wm = w >> 2, wn = w & 3;
  int li = l & 15, grp = l >> 4;

  f32x4 acc[4][4] = {};

  const float* Af = (const float*)A_;
  const unsigned short* Ab = (const unsigned short*)A_;

  // glds lane map: within chunk c (8 rows, 1KB): row = 8c+(l>>3); linear dest
  // slot l&7; source seg pre-swizzled = (l&7)^(row&7), row&7 = (l>>3)&7.
  int grow = l >> 3;
  int gseg = (l & 7) ^ grow;

  // f32-A staging: thread covers row rA = tid>>2 (0..127), 16 f32 at q*16.
  int rA = tid >> 2, q = tid & 3;

  f32x4 areg[4];
  if constexpr (AF32) {
#pragma unroll
    for (int j = 0; j < 4; ++j)
      areg[j] = *(const f32x4*)(Af + (size_t)(m0 + rA) * 1024 + q * 16 + j * 4);
  }

  for (int kt = 0; kt < 16; ++kt) {
    int k0 = kt * 64;
    // ---- stage A ----
    if constexpr (AF32) {
      uint4v w0, w1;
      w0[0] = cvt_pk_bf16(areg[0][0], areg[0][1]);
      w0[1] = cvt_pk_bf16(areg[0][2], areg[0][3]);
      w0[2] = cvt_pk_bf16(areg[1][0], areg[1][1]);
      w0[3] = cvt_pk_bf16(areg[1][2], areg[1][3]);
      w1[0] = cvt_pk_bf16(areg[2][0], areg[2][1]);
      w1[1] = cvt_pk_bf16(areg[2][2], areg[2][3]);
      w1[2] = cvt_pk_bf16(areg[3][0], areg[3][1]);
      w1[3] = cvt_pk_bf16(areg[3][2], areg[3][3]);
      *(uint4v*)((char*)ldsA + rA * 128 + (((2 * q)     ^ (rA & 7)) << 4)) = w0;
      *(uint4v*)((char*)ldsA + rA * 128 + (((2 * q + 1) ^ (rA & 7)) << 4)) = w1;
    } else {
#pragma unroll
      for (int i = 0; i < 2; ++i) {
        int c = w * 2 + i;
        gload_lds16(Ab + (size_t)(m0 + 8 * c + grow) * 1024 + k0 + gseg * 8,
                    (char*)ldsA + c * 1024);
      }
    }
    // ---- stage B ----
#pragma unroll
    for (int i = 0; i < 4; ++i) {
      int c = w * 4 + i;
      gload_lds16(Bt + (size_t)(n0 + 8 * c + grow) * 1024 + k0 + gseg * 8,
                  (char*)ldsB + c * 1024);
    }
    // ---- prefetch next A (f32 path) ----
    if constexpr (AF32) {
      if (kt < 15) {
#pragma unroll
        for (int j = 0; j < 4; ++j)
          areg[j] = *(const f32x4*)(Af + (size_t)(m0 + rA) * 1024 + (k0 + 64) + q * 16 + j * 4);
      }
    }
    __syncthreads();
    // ---- compute: 2 K-subtiles, 16 MFMA each ----
#pragma unroll
    for (int ks = 0; ks < 2; ++ks) {
      short8 af[4], bf[4];
#pragma unroll
      for (int mi = 0; mi < 4; ++mi) {
        int row = wm * 64 + mi * 16 + li;
        af[mi] = *(const short8*)((const char*)ldsA + row * 128 +
                                  (((ks * 4 + grp) ^ (row & 7)) << 4));
      }
#pragma unroll
      for (int ni = 0; ni < 4; ++ni) {
        int row = wn * 64 + ni * 16 + li;
        bf[ni] = *(const short8*)((const char*)ldsB + row * 128 +
                                  (((ks * 4 + grp) ^ (row & 7)) << 4));
      }
#pragma unroll
      for (int mi = 0; mi < 4; ++mi)
#pragma unroll
        for (int ni = 0; ni < 4; ++ni)
          acc[mi][ni] = MFMA_BF16(af[mi], bf[ni], acc[mi][ni]);
    }
    __syncthreads();
  }

  // ---- epilogue ----
  int mrow0 = m0 + wm * 64;   // 64-aligned -> single batch b per wave
  int ncol0 = n0 + wn * 64;   // 64-aligned -> single head h per wave
  float bvv[4];
#pragma unroll
  for (int ni = 0; ni < 4; ++ni) bvv[ni] = bias[ncol0 + ni * 16 + li];

  if constexpr (MODE == 2) {
    float* C = (float*)C_;
#pragma unroll
    for (int mi = 0; mi < 4; ++mi)
#pragma unroll
      for (int ni = 0; ni < 4; ++ni)
#pragma unroll
        for (int j = 0; j < 4; ++j)
          C[(size_t)(mrow0 + mi * 16 + grp * 4 + j) * 1024 + ncol0 + ni * 16 + li] =
              acc[mi][ni][j] + bvv[ni];
  } else if constexpr (MODE == 0) {
    unsigned short* C = (unsigned short*)C_;
    int b = mrow0 >> 6, h = ncol0 >> 6;
    unsigned short* base = C + (size_t)b * 65536 + (size_t)h * 4096;  // [b][h][s][d]
#pragma unroll
    for (int mi = 0; mi < 4; ++mi)
#pragma unroll
      for (int ni = 0; ni < 4; ++ni)
#pragma unroll
        for (int j = 0; j < 4; ++j) {
          float v = acc[mi][ni][j] + bvv[ni];
          v = fmaxf(v, 0.0f);  // ReLU on Q/K
          base[(mi * 16 + grp * 4 + j) * 64 + ni * 16 + li] = bf16_of(v);
        }
  } else {  // MODE 1: V, transposed store [b][h][d][s]
    unsigned short* C = (unsigned short*)C_;
    int b = mrow0 >> 6, h = ncol0 >> 6;
    unsigned short* base = C + (size_t)b * 65536 + (size_t)h * 4096;
#pragma unroll
    for (int mi = 0; mi < 4; ++mi)
#pragma unroll
      for (int ni = 0; ni < 4; ++ni) {
        uint2v pk;
        pk.x = cvt_pk_bf16(acc[mi][ni][0] + bvv[ni], acc[mi][ni][1] + bvv[ni]);
        pk.y = cvt_pk_bf16(acc[mi][ni][2] + bvv[ni], acc[mi][ni][3] + bvv[ni]);
        // d = ni*16+li (row of Vt), s = mi*16 + grp*4 .. +3 (4 consecutive)
        *(uint2v*)(base + (ni * 16 + li) * 64 + mi * 16 + grp * 4) = pk;
      }
  }
}

// ---------------------------------------------------------------------------
// K3: attention. One wave per (b,h). Q,K: [b][h][s][d] bf16 (ReLU'd, biased),
// V: [b][h][d][s] bf16. Out: [b][s][h][d] bf16.
// ---------------------------------------------------------------------------
__global__ __launch_bounds__(64)
void attn_kernel(const unsigned short* __restrict__ qw,
                 const unsigned short* __restrict__ kw,
                 const unsigned short* __restrict__ vw,
                 unsigned short* __restrict__ aw) {
  __shared__ unsigned short p_lds[64 * 72];
  int bh = blockIdx.x;
  int b = bh >> 4, h = bh & 15;
  int l = threadIdx.x;
  int li = l & 15, grp = l >> 4;
  const unsigned short* qb = qw + (size_t)bh * 4096;
  const unsigned short* kb = kw + (size_t)bh * 4096;
  const unsigned short* vb = vw + (size_t)bh * 4096;

  short8 aq[4][2], bk_[4][2];
#pragma unroll
  for (int mi = 0; mi < 4; ++mi)
#pragma unroll
    for (int ks = 0; ks < 2; ++ks) {
      aq[mi][ks]  = *(const short8*)(qb + (mi * 16 + li) * 64 + ks * 32 + grp * 8);
      bk_[mi][ks] = *(const short8*)(kb + (mi * 16 + li) * 64 + ks * 32 + grp * 8);
    }

  f32x4 sf[4][4];
#pragma unroll
  for (int mi = 0; mi < 4; ++mi)
#pragma unroll
    for (int ni = 0; ni < 4; ++ni) {
      f32x4 t = {};
      t = MFMA_BF16(aq[mi][0], bk_[ni][0], t);
      t = MFMA_BF16(aq[mi][1], bk_[ni][1], t);
      sf[mi][ni] = t;
    }

#pragma unroll
  for (int mi = 0; mi < 4; ++mi) {
#pragma unroll
    for (int j = 0; j < 4; ++j) {
      int row = mi * 16 + grp * 4 + j;
      float mx = -1e30f;
#pragma unroll
      for (int ni = 0; ni < 4; ++ni) {
        int col = ni * 16 + li;
        float v = sf[mi][ni][j] * 0.125f;
        v = (col <= row) ? v : -1e30f;
        sf[mi][ni][j] = v;
        mx = fmaxf(mx, v);
      }
#pragma unroll
      for (int sh = 1; sh < 16; sh <<= 1) mx = fmaxf(mx, __shfl_xor(mx, sh, 64));
      float sum = 0.0f;
#pragma unroll
      for (int ni = 0; ni < 4; ++ni) {
        float e = __expf(sf[mi][ni][j] - mx);
        sf[mi][ni][j] = e;
        sum += e;
      }
#pragma unroll
      for (int sh = 1; sh < 16; sh <<= 1) sum += __shfl_xor(sum, sh, 64);
      float rr = 1.0f / sum;
#pragma unroll
      for (int ni = 0; ni < 4; ++ni) sf[mi][ni][j] *= rr;
    }
  }

#pragma unroll
  for (int mi = 0; mi < 4; ++mi)
#pragma unroll
    for (int ni = 0; ni < 4; ++ni)
#pragma unroll
      for (int j = 0; j < 4; ++j)
        p_lds[(mi * 16 + grp * 4 + j) * 72 + ni * 16 + li] = bf16_of(sf[mi][ni][j]);
  __syncthreads();

  short8 pa[4][2], bv_[4][2];
#pragma unroll
  for (int mi = 0; mi < 4; ++mi)
#pragma unroll
    for (int ks = 0; ks < 2; ++ks)
      pa[mi][ks] = *(const short8*)(p_lds + (mi * 16 + li) * 72 + ks * 32 + grp * 8);
#pragma unroll
  for (int ni = 0; ni < 4; ++ni)
#pragma unroll
    for (int ks = 0; ks < 2; ++ks)
      bv_[ni][ks] = *(const short8*)(vb + (ni * 16 + li) * 64 + ks * 32 + grp * 8);

  f32x4 of[4][4];
#pragma unroll
  for (int mi = 0; mi < 4; ++mi)
#pragma unroll
    for (int ni = 0; ni < 4; ++ni) {
      f32x4 t = {};
      t = MFMA_BF16(pa[mi][0], bv_[ni][0], t);
      t = MFMA_BF16(pa[mi][1], bv_[ni][1], t);
      of[mi][ni] = t;
    }

  unsigned short* ab = aw + (size_t)b * 65536 + (size_t)h * 64;
#pragma unroll
  for (int mi = 0; mi < 4; ++mi)
#pragma unroll
    for (int ni = 0; ni < 4; ++ni)
#pragma unroll
      for (int j = 0; j < 4; ++j)
        ab[(size_t)(mi * 16 + grp * 4 + j) * 1024 + ni * 16 + li] = bf16_of(of[mi][ni][j]);
}

// ---------------------------------------------------------------------------
extern "C" void kernel_launch(void* const* d_in, const int* in_sizes, int n_in,
                              void* d_out, int out_size, void* d_ws, size_t ws_size,
                              hipStream_t stream) {
  (void)in_sizes; (void)n_in; (void)out_size; (void)ws_size;
  const float* query = (const float*)d_in[0];
  const float* key   = (const float*)d_in[1];
  const float* value = (const float*)d_in[2];
  const float* Wq = (const float*)d_in[3];
  const float* bq = (const float*)d_in[4];
  const float* Wk = (const float*)d_in[5];
  const float* bk = (const float*)d_in[6];
  const float* Wv = (const float*)d_in[7];
  const float* bv = (const float*)d_in[8];
  const float* Wo = (const float*)d_in[9];
  const float* bo = (const float*)d_in[10];
  float* out = (float*)d_out;

  unsigned short* wt = (unsigned short*)d_ws;
  const size_t NE = (size_t)67108864;  // B*S*E
  unsigned short* qw = wt + (size_t)4 * 1024 * 1024;
  unsigned short* kw = qw + NE;
  unsigned short* vw = kw + NE;
  unsigned short* aw = vw + NE;

  wcast_kernel<<<dim3(16, 16, 4), 256, 0, stream>>>(Wq, Wk, Wv, Wo, wt);
  gemm_kernel<0><<<dim3(2048), 512, 0, stream>>>(query, wt + (size_t)0 * 1048576, bq, qw);
  gemm_kernel<0><<<dim3(2048), 512, 0, stream>>>(key,   wt + (size_t)1 * 1048576, bk, kw);
  gemm_kernel<1><<<dim3(2048), 512, 0, stream>>>(value, wt + (size_t)2 * 1048576, bv, vw);
  attn_kernel<<<dim3(16384), 64, 0, stream>>>(qw, kw, vw, aw);
  gemm_kernel<2><<<dim3(2048), 512, 0, stream>>>(aw, wt + (size_t)3 * 1048576, bo, out);
}